// Round 12
// baseline (2852.027 us; speedup 1.0000x reference)
//
#include <hip/hip_runtime.h>
#include <cmath>

// ---------------------------------------------------------------------------
// LSTM T=512 B=64 I=512 H=512, fp32 in/out, bf16 MFMA compute.
// Phase A: Xg = X@Wx + b  (bf16 MFMA GEMM), output re-laid as [t4g][chunk][b][8]
// Phase B: persistent 32-block scan (v12 = EXACT v7 protocol, single diff:
//   consumer bfrag loads are PLAIN CACHEABLE after an acquire fence
//   (buffer_inv), instead of per-wave sc0sc1 L2-bypass loads. The 4 waves of
//   a block read the SAME 32KB of h; v7 fetched 4 copies from L3 (128KB/CU/
//   step). Release/acquire makes one L3 fetch + L1/L2 hits correct:
//   producer h-stores are write-through-acked to L3 BEFORE the flag, and the
//   acquire invalidates L1/L2 before the plain loads.)
// ---------------------------------------------------------------------------

typedef __attribute__((ext_vector_type(8)))  short   short8;
typedef __attribute__((ext_vector_type(4)))  short   short4v;
typedef __attribute__((ext_vector_type(4)))  float   f32x4;
typedef __attribute__((ext_vector_type(16))) float   f32x16;

#define TSTEPS 512

__device__ __forceinline__ unsigned short f2bf(float f) {
  unsigned u = __builtin_bit_cast(unsigned, f);
  unsigned r = (u + 0x7FFFu + ((u >> 16) & 1u)) >> 16;
  return (unsigned short)r;
}
__device__ __forceinline__ float bf2f(unsigned short s) {
  unsigned u = ((unsigned)s) << 16;
  return __builtin_bit_cast(float, u);
}
__device__ __forceinline__ void gload_lds16(const void* g, void* l) {
  __builtin_amdgcn_global_load_lds(
      (const __attribute__((address_space(1))) unsigned int*)g,
      (__attribute__((address_space(3))) unsigned int*)l, 16, 0, 0);
}
__device__ __forceinline__ float sigmoid_fast(float x) {
  return 1.0f / (1.0f + __expf(-x));
}
__device__ __forceinline__ float tanh_fast(float x) {
  float e = __expf(2.0f * x);
  return 1.0f - 2.0f / (e + 1.0f);
}

// ---------------------------------------------------------------------------
// Prep: transpose+convert weights [512][512] f32 (k-major) -> bf16 [g*512+h][k]
// ---------------------------------------------------------------------------
__global__ __launch_bounds__(256) void prep_wT(
    const float* __restrict__ Wax, const float* __restrict__ Wix,
    const float* __restrict__ Wfx, const float* __restrict__ Wox,
    const float* __restrict__ Wah, const float* __restrict__ Wih,
    const float* __restrict__ Wfh, const float* __restrict__ Woh,
    unsigned short* __restrict__ WxT, unsigned short* __restrict__ WhT) {
  __shared__ float tile[32][33];
  int bx = blockIdx.x;              // 8 mats * 256 tiles
  int mat = bx >> 8;
  int t32 = bx & 255;
  int k0 = (t32 & 15) * 32;
  int h0 = (t32 >> 4) * 32;
  const float* S =
      (mat == 0) ? Wax : (mat == 1) ? Wix : (mat == 2) ? Wfx :
      (mat == 3) ? Wox : (mat == 4) ? Wah : (mat == 5) ? Wih :
      (mat == 6) ? Wfh : Woh;
  unsigned short* D = (mat < 4) ? WxT : WhT;
  int g = mat & 3;
  int tx = threadIdx.x & 31, ty = threadIdx.x >> 5;  // ty in [0,8)
#pragma unroll
  for (int r = 0; r < 4; ++r)
    tile[ty + r * 8][tx] = S[(size_t)(k0 + ty + r * 8) * 512 + h0 + tx];
  __syncthreads();
#pragma unroll
  for (int r = 0; r < 4; ++r) {
    int h = h0 + ty + r * 8;
    int k = k0 + tx;
    D[((size_t)(g * 512 + h) << 9) + k] = f2bf(tile[tx][ty + r * 8]);
  }
}

// X f32 [32768][512] -> bf16
__global__ __launch_bounds__(256) void prep_xbf(const float* __restrict__ X,
                                                unsigned short* __restrict__ Xbf) {
  size_t i = (size_t)blockIdx.x * 256 + threadIdx.x;
  f32x4 v = *(const f32x4*)(X + i * 4);
  short4v o;
  o[0] = (short)f2bf(v[0]); o[1] = (short)f2bf(v[1]);
  o[2] = (short)f2bf(v[2]); o[3] = (short)f2bf(v[3]);
  *(short4v*)(Xbf + i * 4) = o;
}

__global__ __launch_bounds__(256) void prep_bias(
    const float* __restrict__ ba, const float* __restrict__ bi,
    const float* __restrict__ bf, const float* __restrict__ bo,
    float* __restrict__ biascat) {
  int n = blockIdx.x * 256 + threadIdx.x;  // [0,2048)
  int g = n >> 9, h = n & 511;
  const float* s = (g == 0) ? ba : (g == 1) ? bi : (g == 2) ? bf : bo;
  biascat[n] = s[h];
}

// ---------------------------------------------------------------------------
// Phase A: Xg = Xbf @ WxT^T + bias, output layout [t*4+g][h/8][b][h%8] bf16.
// ---------------------------------------------------------------------------
__global__ __launch_bounds__(256) void gemm_xproj(
    const unsigned short* __restrict__ Xbf,   // [32768][512]
    const unsigned short* __restrict__ WxT,   // [2048][512]
    const float* __restrict__ biascat,        // [2048]
    unsigned short* __restrict__ Xg) {        // [2048][64][64][8] bf16
  __shared__ unsigned short Asm[128 * 64];
  __shared__ unsigned short Bsm[128 * 64];
  int bx = blockIdx.x;
  int nt = bx & 15, mt = bx >> 4;
  int m0 = mt * 128, n0 = nt * 128;
  int tid = threadIdx.x;
  int w = tid >> 6, l = tid & 63;
  int wm = (w >> 1) * 64, wn = (w & 1) * 64;
  f32x4 acc[4][4] = {};

  for (int ks = 0; ks < 8; ++ks) {
    int k0 = ks * 64;
    __syncthreads();
    int lr = l >> 3;
    int ksl = ((l & 7) ^ lr) * 8;
#pragma unroll
    for (int ii = 0; ii < 4; ++ii) {
      int i = w * 4 + ii;
      int r = i * 8 + lr;
      gload_lds16(Xbf + (size_t)(m0 + r) * 512 + k0 + ksl, Asm + i * 512 + l * 8);
    }
#pragma unroll
    for (int ii = 0; ii < 4; ++ii) {
      int i = w * 4 + ii;
      int r = i * 8 + lr;
      gload_lds16(WxT + (size_t)(n0 + r) * 512 + k0 + ksl, Bsm + i * 512 + l * 8);
    }
    __syncthreads();
#pragma unroll
    for (int kk = 0; kk < 2; ++kk) {
      short8 af[4], bfr[4];
#pragma unroll
      for (int mi = 0; mi < 4; ++mi) {
        int row = wm + mi * 16 + (l & 15);
        int slot = (kk * 4 + (l >> 4)) ^ (row & 7);
        af[mi] = *(const short8*)(Asm + row * 64 + slot * 8);
      }
#pragma unroll
      for (int ni = 0; ni < 4; ++ni) {
        int row = wn + ni * 16 + (l & 15);
        int slot = (kk * 4 + (l >> 4)) ^ (row & 7);
        bfr[ni] = *(const short8*)(Bsm + row * 64 + slot * 8);
      }
#pragma unroll
      for (int mi = 0; mi < 4; ++mi)
#pragma unroll
        for (int ni = 0; ni < 4; ++ni)
          acc[mi][ni] = __builtin_amdgcn_mfma_f32_16x16x32_bf16(
              af[mi], bfr[ni], acc[mi][ni], 0, 0, 0);
    }
  }
  // epilogue: C/D col=l&15, row=(l>>4)*4+r; write [t4g][chunk][b][e] layout
#pragma unroll
  for (int mi = 0; mi < 4; ++mi)
#pragma unroll
    for (int ni = 0; ni < 4; ++ni) {
      int col = n0 + wn + ni * 16 + (l & 15);
      float bias = biascat[col];
      int g = col >> 9, h = col & 511;
      int chunk = h >> 3, e = h & 7;
#pragma unroll
      for (int r = 0; r < 4; ++r) {
        int m = m0 + wm + mi * 16 + (l >> 4) * 4 + r;
        int t = m >> 6, b = m & 63;
        Xg[(((size_t)(t * 4 + g) * 64 + chunk) * 64 + b) * 8 + e] =
            f2bf(acc[mi][ni][r] + bias);
      }
    }
}

// ---------------------------------------------------------------------------
// Phase B: persistent scan v12. 32 blocks x 4 waves. Protocol == v7.
// Block j: batch group mi=j&1 (rows mi*32..+31), col chunk cc=j>>1.
// Wave w owns 8 hcols x 4 gates; swapped MFMA (A=WhT regs, B=h) -> gates
// lane-local. hbuf: [parity][chunk64][b64][8] bf16; producer stores sc0sc1
// (write-through to L3) + vmcnt ack + syncthreads + relaxed block flag.
// Consumer: relaxed 16-line poll -> acquire fence (cache inv) -> PLAIN
// cacheable bfrag loads (4 waves share one 32KB L3 fetch via L1/L2).
// ---------------------------------------------------------------------------
__global__ __launch_bounds__(256, 1) void lstm_scan(
    const unsigned short* __restrict__ Xg,   // [2048][64][64][8] bf16
    const unsigned short* __restrict__ WhT,  // [2048][512] bf16
    unsigned short* __restrict__ hbuf,       // [2][64][64][8] bf16 (no init)
    int* __restrict__ flags,                 // [32*32] ints, zeroed
    float* __restrict__ out) {               // [512][64][512] f32
  const int j = blockIdx.x;   // 0..31
  const int mi = j & 1;
  const int cc = j >> 1;
  const int tid = threadIdx.x;
  const int w = tid >> 6, l = tid & 63;

  // ---- recurrent weights as A-fragments (registers / compiler JIT) ----
  short8 wf[32];
  {
    const int m = l & 31;
    const int g = m >> 3;
    const int hcol_w = cc * 32 + w * 8 + (m & 7);
    const unsigned short* base =
        WhT + (((size_t)(g * 512 + hcol_w)) << 9) + (l >> 5) * 8;
#pragma unroll
    for (int kt = 0; kt < 32; ++kt) wf[kt] = *(const short8*)(base + kt * 16);
  }

  const int b = mi * 32 + (l & 31);          // this lane's batch row
  const int hcol0 = cc * 32 + w * 8 + (l >> 5) * 4;  // first of 4 hcols
  const int mychunk = cc * 4 + w;

  // B-frag load element offset: chunk=(kt*2+(l>>5)), row b -> elements
  const int ld_eoff0 = (l >> 5) * 512 + b * 8;       // elements (x2 = bytes)
  // h store voffset (bytes): chunk=mychunk, row b, half (l>>5)
  const unsigned st_voff = (unsigned)(mychunk * 1024 + b * 16 + (l >> 5) * 8);

  // per-BLOCK flag, 128B stride: group mi's 16 block-flags on 16 lines
  int* const myflag = flags + (mi * 16 + cc) * 32;
  int* const pollflag = flags + (mi * 16 + (l & 15)) * 32;

  float s4[4] = {0.f, 0.f, 0.f, 0.f};  // cell state, registers, all steps

  // Xg for t=0, preloaded
  uint2 xgn[4];
#pragma unroll
  for (int g = 0; g < 4; ++g)
    xgn[g] = *(const uint2*)(Xg +
        ((((size_t)(0 * 4 + g) * 64 + mychunk) * 64 + b) * 8 + (l >> 5) * 4));

#pragma unroll 1
  for (int t = 0; t < TSTEPS; ++t) {
    f32x16 asum = {};
    if (t > 0) {
      // ---- wait for all 16 producer blocks of this batch group ----
      int fv;
      do {
        fv = __hip_atomic_load(pollflag, __ATOMIC_RELAXED,
                               __HIP_MEMORY_SCOPE_AGENT);
      } while (!__all(fv >= t));
      // upgrade the passing relaxed poll to an acquire: invalidates L1/L2
      // so the following PLAIN loads must fetch fresh lines from L3.
      __builtin_amdgcn_fence(__ATOMIC_ACQUIRE, "agent");
      // ---- load 32 B-fragments (plain cacheable; waves share via L1/L2) ----
      const unsigned short* hbase = hbuf + (size_t)((t - 1) & 1) * 32768;
      short8 bfrag[32];
#pragma unroll
      for (int kt = 0; kt < 32; ++kt)
        bfrag[kt] = *(const short8*)(hbase + ld_eoff0 + kt * 1024);
      // ---- 32 MFMAs, 2 interleaved accumulators ----
      f32x16 a0 = {}, a1 = {};
#pragma unroll
      for (int kt = 0; kt < 32; kt += 2) {
        a0 = __builtin_amdgcn_mfma_f32_32x32x16_bf16(wf[kt], bfrag[kt], a0,
                                                     0, 0, 0);
        a1 = __builtin_amdgcn_mfma_f32_32x32x16_bf16(wf[kt + 1], bfrag[kt + 1],
                                                     a1, 0, 0, 0);
      }
      asum = a0 + a1;
    }
    // ---- gates: asum[r]: gate g=r>>2, q=r&3 (cols hcol0+q), batch b ----
    float hout[4];
#pragma unroll
    for (int q = 0; q < 4; ++q) {
      float pa = asum[0 * 4 + q] + bf2f((unsigned short)((q < 2 ? xgn[0].x : xgn[0].y) >> ((q & 1) * 16)));
      float pi = asum[1 * 4 + q] + bf2f((unsigned short)((q < 2 ? xgn[1].x : xgn[1].y) >> ((q & 1) * 16)));
      float pf = asum[2 * 4 + q] + bf2f((unsigned short)((q < 2 ? xgn[2].x : xgn[2].y) >> ((q & 1) * 16)));
      float po = asum[3 * 4 + q] + bf2f((unsigned short)((q < 2 ? xgn[3].x : xgn[3].y) >> ((q & 1) * 16)));
      float a  = tanh_fast(pa);
      float ig = sigmoid_fast(pi);
      float fg = sigmoid_fast(pf);
      float og = sigmoid_fast(po);
      s4[q] = a * ig + s4[q] * fg;
      hout[q] = tanh_fast(s4[q]) * og;
    }
    // ---- publish h(t): coalesced 8B sc0sc1 store; block-aggregate flag ----
    {
      unsigned lo = (unsigned)f2bf(hout[0]) | ((unsigned)f2bf(hout[1]) << 16);
      unsigned hi = (unsigned)f2bf(hout[2]) | ((unsigned)f2bf(hout[3]) << 16);
      uint2 hd; hd.x = lo; hd.y = hi;
      const unsigned short* sbase = hbuf + (size_t)(t & 1) * 32768;
      asm volatile("global_store_dwordx2 %0, %1, %2 sc0 sc1"
                   :: "v"(st_voff), "v"(hd), "s"(sbase) : "memory");
      asm volatile("s_waitcnt vmcnt(0)" ::: "memory");
      __syncthreads();  // all 4 waves' h-stores are at the coherence point
      if (tid == 0)
        __hip_atomic_store(myflag, t + 1, __ATOMIC_RELAXED,
                           __HIP_MEMORY_SCOPE_AGENT);
    }
    // ---- off critical path: out store + next Xg prefetch ----
    f32x4 ov;
    ov[0] = hout[0]; ov[1] = hout[1]; ov[2] = hout[2]; ov[3] = hout[3];
    *(f32x4*)(out + ((size_t)t * 64 + b) * 512 + hcol0) = ov;
    const int tn = (t + 1 < TSTEPS) ? t + 1 : t;
#pragma unroll
    for (int g = 0; g < 4; ++g)
      xgn[g] = *(const uint2*)(Xg +
          ((((size_t)(tn * 4 + g) * 64 + mychunk) * 64 + b) * 8 + (l >> 5) * 4));
  }
}

// ---------------------------------------------------------------------------
// Workspace layout (bytes):
//   0          Xg bf16     134217728
//   134217728  Xbf bf16     33554432  (dead after gemm_xproj)
//   134217728  hbuf bf16      262144  (overlaps Xbf; no init needed)
//   167772160  WxT bf16      2097152
//   169869312  WhT bf16      2097152
//   171966464  biascat f32      8192
//   171974656  flags            4096  (zeroed)
// ---------------------------------------------------------------------------
extern "C" void kernel_launch(void* const* d_in, const int* in_sizes, int n_in,
                              void* d_out, int out_size, void* d_ws,
                              size_t ws_size, hipStream_t stream) {
  const float* X   = (const float*)d_in[0];
  const float* Wax = (const float*)d_in[1];
  const float* Wix = (const float*)d_in[2];
  const float* Wfx = (const float*)d_in[3];
  const float* Wox = (const float*)d_in[4];
  const float* Wah = (const float*)d_in[5];
  const float* Wih = (const float*)d_in[6];
  const float* Wfh = (const float*)d_in[7];
  const float* Woh = (const float*)d_in[8];
  const float* ba  = (const float*)d_in[9];
  const float* bi  = (const float*)d_in[10];
  const float* bf  = (const float*)d_in[11];
  const float* bo  = (const float*)d_in[12];

  char* ws = (char*)d_ws;
  unsigned short* Xg   = (unsigned short*)(ws);
  unsigned short* Xbf  = (unsigned short*)(ws + 134217728);
  unsigned short* hbuf = (unsigned short*)(ws + 134217728);  // reuses Xbf
  unsigned short* WxT  = (unsigned short*)(ws + 167772160);
  unsigned short* WhT  = (unsigned short*)(ws + 169869312);
  float*          bcat = (float*)(ws + 171966464);
  int*            flags= (int*)(ws + 171974656);

  hipMemsetAsync(ws + 171974656, 0, 4096, stream);  // flags = 0

  prep_wT<<<2048, 256, 0, stream>>>(Wax, Wix, Wfx, Wox, Wah, Wih, Wfh, Woh,
                                    WxT, WhT);
  prep_xbf<<<16384, 256, 0, stream>>>(X, Xbf);
  prep_bias<<<8, 256, 0, stream>>>(ba, bi, bf, bo, bcat);
  gemm_xproj<<<4096, 256, 0, stream>>>(Xbf, WxT, bcat, Xg);
  lstm_scan<<<32, 256, 0, stream>>>(Xg, WhT, hbuf, flags, (float*)d_out);
}

// Round 13
// 1716.517 us; speedup vs baseline: 1.6615x; 1.6615x over previous
//
#include <hip/hip_runtime.h>
#include <cmath>

// ---------------------------------------------------------------------------
// LSTM T=512 B=64 I=512 H=512, fp32 in/out, bf16 MFMA compute.
// Phase A: Xg = X@Wx + b  (bf16 MFMA GEMM), output re-laid as [t4g][chunk][b][8]
// Phase B: persistent 32-block scan (v13 = EXACT v7 protocol, single diff:
//   the 4 waves of a block issued IDENTICAL sc0sc1 bfrag loads (128KB/CU/step
//   from L3 -- the dominant unmodeled cost, confirmed by v12). v13 stages h
//   into LDS once per block (reg-staged coherent loads + ds_write, parity
//   double-buffered), then bfrags come from ds_read_b128. 4x less L3 traffic.
//   No fences -- v12's mistake (per-step cache invalidate killed the L2
//   weight stream) is not repeated.)
// ---------------------------------------------------------------------------

typedef __attribute__((ext_vector_type(8)))  short   short8;
typedef __attribute__((ext_vector_type(4)))  short   short4v;
typedef __attribute__((ext_vector_type(4)))  float   f32x4;
typedef __attribute__((ext_vector_type(16))) float   f32x16;

#define TSTEPS 512

__device__ __forceinline__ unsigned short f2bf(float f) {
  unsigned u = __builtin_bit_cast(unsigned, f);
  unsigned r = (u + 0x7FFFu + ((u >> 16) & 1u)) >> 16;
  return (unsigned short)r;
}
__device__ __forceinline__ float bf2f(unsigned short s) {
  unsigned u = ((unsigned)s) << 16;
  return __builtin_bit_cast(float, u);
}
__device__ __forceinline__ void gload_lds16(const void* g, void* l) {
  __builtin_amdgcn_global_load_lds(
      (const __attribute__((address_space(1))) unsigned int*)g,
      (__attribute__((address_space(3))) unsigned int*)l, 16, 0, 0);
}
__device__ __forceinline__ float sigmoid_fast(float x) {
  return 1.0f / (1.0f + __expf(-x));
}
__device__ __forceinline__ float tanh_fast(float x) {
  float e = __expf(2.0f * x);
  return 1.0f - 2.0f / (e + 1.0f);
}

// ---------------------------------------------------------------------------
// Prep: transpose+convert weights [512][512] f32 (k-major) -> bf16 [g*512+h][k]
// ---------------------------------------------------------------------------
__global__ __launch_bounds__(256) void prep_wT(
    const float* __restrict__ Wax, const float* __restrict__ Wix,
    const float* __restrict__ Wfx, const float* __restrict__ Wox,
    const float* __restrict__ Wah, const float* __restrict__ Wih,
    const float* __restrict__ Wfh, const float* __restrict__ Woh,
    unsigned short* __restrict__ WxT, unsigned short* __restrict__ WhT) {
  __shared__ float tile[32][33];
  int bx = blockIdx.x;              // 8 mats * 256 tiles
  int mat = bx >> 8;
  int t32 = bx & 255;
  int k0 = (t32 & 15) * 32;
  int h0 = (t32 >> 4) * 32;
  const float* S =
      (mat == 0) ? Wax : (mat == 1) ? Wix : (mat == 2) ? Wfx :
      (mat == 3) ? Wox : (mat == 4) ? Wah : (mat == 5) ? Wih :
      (mat == 6) ? Wfh : Woh;
  unsigned short* D = (mat < 4) ? WxT : WhT;
  int g = mat & 3;
  int tx = threadIdx.x & 31, ty = threadIdx.x >> 5;  // ty in [0,8)
#pragma unroll
  for (int r = 0; r < 4; ++r)
    tile[ty + r * 8][tx] = S[(size_t)(k0 + ty + r * 8) * 512 + h0 + tx];
  __syncthreads();
#pragma unroll
  for (int r = 0; r < 4; ++r) {
    int h = h0 + ty + r * 8;
    int k = k0 + tx;
    D[((size_t)(g * 512 + h) << 9) + k] = f2bf(tile[tx][ty + r * 8]);
  }
}

// X f32 [32768][512] -> bf16
__global__ __launch_bounds__(256) void prep_xbf(const float* __restrict__ X,
                                                unsigned short* __restrict__ Xbf) {
  size_t i = (size_t)blockIdx.x * 256 + threadIdx.x;
  f32x4 v = *(const f32x4*)(X + i * 4);
  short4v o;
  o[0] = (short)f2bf(v[0]); o[1] = (short)f2bf(v[1]);
  o[2] = (short)f2bf(v[2]); o[3] = (short)f2bf(v[3]);
  *(short4v*)(Xbf + i * 4) = o;
}

__global__ __launch_bounds__(256) void prep_bias(
    const float* __restrict__ ba, const float* __restrict__ bi,
    const float* __restrict__ bf, const float* __restrict__ bo,
    float* __restrict__ biascat) {
  int n = blockIdx.x * 256 + threadIdx.x;  // [0,2048)
  int g = n >> 9, h = n & 511;
  const float* s = (g == 0) ? ba : (g == 1) ? bi : (g == 2) ? bf : bo;
  biascat[n] = s[h];
}

// ---------------------------------------------------------------------------
// Phase A: Xg = Xbf @ WxT^T + bias, output layout [t*4+g][h/8][b][h%8] bf16.
// ---------------------------------------------------------------------------
__global__ __launch_bounds__(256) void gemm_xproj(
    const unsigned short* __restrict__ Xbf,   // [32768][512]
    const unsigned short* __restrict__ WxT,   // [2048][512]
    const float* __restrict__ biascat,        // [2048]
    unsigned short* __restrict__ Xg) {        // [2048][64][64][8] bf16
  __shared__ unsigned short Asm[128 * 64];
  __shared__ unsigned short Bsm[128 * 64];
  int bx = blockIdx.x;
  int nt = bx & 15, mt = bx >> 4;
  int m0 = mt * 128, n0 = nt * 128;
  int tid = threadIdx.x;
  int w = tid >> 6, l = tid & 63;
  int wm = (w >> 1) * 64, wn = (w & 1) * 64;
  f32x4 acc[4][4] = {};

  for (int ks = 0; ks < 8; ++ks) {
    int k0 = ks * 64;
    __syncthreads();
    int lr = l >> 3;
    int ksl = ((l & 7) ^ lr) * 8;
#pragma unroll
    for (int ii = 0; ii < 4; ++ii) {
      int i = w * 4 + ii;
      int r = i * 8 + lr;
      gload_lds16(Xbf + (size_t)(m0 + r) * 512 + k0 + ksl, Asm + i * 512 + l * 8);
    }
#pragma unroll
    for (int ii = 0; ii < 4; ++ii) {
      int i = w * 4 + ii;
      int r = i * 8 + lr;
      gload_lds16(WxT + (size_t)(n0 + r) * 512 + k0 + ksl, Bsm + i * 512 + l * 8);
    }
    __syncthreads();
#pragma unroll
    for (int kk = 0; kk < 2; ++kk) {
      short8 af[4], bfr[4];
#pragma unroll
      for (int mi = 0; mi < 4; ++mi) {
        int row = wm + mi * 16 + (l & 15);
        int slot = (kk * 4 + (l >> 4)) ^ (row & 7);
        af[mi] = *(const short8*)(Asm + row * 64 + slot * 8);
      }
#pragma unroll
      for (int ni = 0; ni < 4; ++ni) {
        int row = wn + ni * 16 + (l & 15);
        int slot = (kk * 4 + (l >> 4)) ^ (row & 7);
        bfr[ni] = *(const short8*)(Bsm + row * 64 + slot * 8);
      }
#pragma unroll
      for (int mi = 0; mi < 4; ++mi)
#pragma unroll
        for (int ni = 0; ni < 4; ++ni)
          acc[mi][ni] = __builtin_amdgcn_mfma_f32_16x16x32_bf16(
              af[mi], bfr[ni], acc[mi][ni], 0, 0, 0);
    }
  }
  // epilogue: C/D col=l&15, row=(l>>4)*4+r; write [t4g][chunk][b][e] layout
#pragma unroll
  for (int mi = 0; mi < 4; ++mi)
#pragma unroll
    for (int ni = 0; ni < 4; ++ni) {
      int col = n0 + wn + ni * 16 + (l & 15);
      float bias = biascat[col];
      int g = col >> 9, h = col & 511;
      int chunk = h >> 3, e = h & 7;
#pragma unroll
      for (int r = 0; r < 4; ++r) {
        int m = m0 + wm + mi * 16 + (l >> 4) * 4 + r;
        int t = m >> 6, b = m & 63;
        Xg[(((size_t)(t * 4 + g) * 64 + chunk) * 64 + b) * 8 + e] =
            f2bf(acc[mi][ni][r] + bias);
      }
    }
}

// ---------------------------------------------------------------------------
// Phase B: persistent scan v13. 32 blocks x 4 waves. Protocol == v7.
// Block j: batch group mi=j&1 (rows mi*32..+31), col chunk cc=j>>1.
// Wave w owns 8 hcols x 4 gates; swapped MFMA (A=WhT regs/L2, B=h from LDS).
// h handoff: hbuf[parity][chunk64][b64][8] bf16 sc0sc1 + ack + block flag
// (exactly v7). Consumer: poll -> cooperative reg-stage of the block's 32KB
// h slice into parity-dbuf LDS (each wave 8 chunk-pairs) -> __syncthreads ->
// ds_read_b128 bfrags. L3 read traffic per CU per step: 128KB -> 32KB.
// ---------------------------------------------------------------------------
__global__ __launch_bounds__(256, 1) void lstm_scan(
    const unsigned short* __restrict__ Xg,   // [2048][64][64][8] bf16
    const unsigned short* __restrict__ WhT,  // [2048][512] bf16
    unsigned short* __restrict__ hbuf,       // [2][64][64][8] bf16 (no init)
    int* __restrict__ flags,                 // [32*32] ints, zeroed
    float* __restrict__ out) {               // [512][64][512] f32
  // parity-double-buffered staged h: [2][chunk 64][local row 32][8] bf16
  __shared__ unsigned short hsm[2][64 * 32 * 8];   // 2 x 32 KiB
  const int j = blockIdx.x;   // 0..31
  const int mi = j & 1;
  const int cc = j >> 1;
  const int tid = threadIdx.x;
  const int w = tid >> 6, l = tid & 63;

  // ---- recurrent weights as A-fragments (registers / compiler L2 stream) ----
  short8 wf[32];
  {
    const int m = l & 31;
    const int g = m >> 3;
    const int hcol_w = cc * 32 + w * 8 + (m & 7);
    const unsigned short* base =
        WhT + (((size_t)(g * 512 + hcol_w)) << 9) + (l >> 5) * 8;
#pragma unroll
    for (int kt = 0; kt < 32; ++kt) wf[kt] = *(const short8*)(base + kt * 16);
  }

  const int b = mi * 32 + (l & 31);          // this lane's batch row
  const int hcol0 = cc * 32 + w * 8 + (l >> 5) * 4;  // first of 4 hcols
  const int mychunk = cc * 4 + w;

  // staging: instr (w,i) covers chunks (w*8+i)*2 + (l>>5), row mi*32+(l&31)
  const unsigned stg_goff0 = (unsigned)((l >> 5) * 1024 + (mi * 32 + (l & 31)) * 16);
  // LDS dest byte offset for instr i: (w*8+i)*1024 + l*16
  const int stg_loff0 = w * 8192 + l * 16;
  // bfrag ds_read byte offset: chunk=(kt*2+(l>>5)), local row l&31
  const int ld_loff0 = (l >> 5) * 512 + (l & 31) * 16;
  // h store voffset (bytes): chunk=mychunk, row b, half (l>>5)
  const unsigned st_voff = (unsigned)(mychunk * 1024 + b * 16 + (l >> 5) * 8);

  // per-BLOCK flag, 128B stride: group mi's 16 block-flags on 16 lines
  int* const myflag = flags + (mi * 16 + cc) * 32;
  int* const pollflag = flags + (mi * 16 + (l & 15)) * 32;

  float s4[4] = {0.f, 0.f, 0.f, 0.f};  // cell state, registers, all steps

  // Xg for t=0, preloaded
  uint2 xgn[4];
#pragma unroll
  for (int g = 0; g < 4; ++g)
    xgn[g] = *(const uint2*)(Xg +
        ((((size_t)(0 * 4 + g) * 64 + mychunk) * 64 + b) * 8 + (l >> 5) * 4));

#pragma unroll 1
  for (int t = 0; t < TSTEPS; ++t) {
    f32x16 asum = {};
    if (t > 0) {
      // ---- wait for all 16 producer blocks of this batch group ----
      int fv;
      do {
        fv = __hip_atomic_load(pollflag, __ATOMIC_RELAXED,
                               __HIP_MEMORY_SCOPE_AGENT);
      } while (!__all(fv >= t));
      asm volatile("" ::: "memory");
      // ---- cooperative stage: 8 coherent loads + 8 ds_writes per wave ----
      const unsigned short* hbase = hbuf + (size_t)((t - 1) & 1) * 32768;
      unsigned short* hs = hsm[(t - 1) & 1];
      short8 tmp[8];
#pragma unroll
      for (int i = 0; i < 8; ++i) {
        asm volatile("global_load_dwordx4 %0, %1, %2 sc0 sc1"
                     : "=v"(tmp[i])
                     : "v"(stg_goff0 + (unsigned)((w * 8 + i) * 2048)),
                       "s"(hbase));
      }
      asm volatile("s_waitcnt vmcnt(0)" ::: "memory");
      __builtin_amdgcn_sched_barrier(0);
#pragma unroll
      for (int i = 0; i < 8; ++i)
        *(short8*)((char*)hs + stg_loff0 + i * 1024) = tmp[i];
      __syncthreads();  // staging visible to all 4 waves
      // ---- 32 MFMAs, bfrags from LDS (compiler interleaves lgkmcnt) ----
      f32x16 a0 = {}, a1 = {};
#pragma unroll
      for (int kt = 0; kt < 32; kt += 2) {
        short8 b0 = *(const short8*)((const char*)hs + ld_loff0 + kt * 1024);
        short8 b1 = *(const short8*)((const char*)hs + ld_loff0 + (kt + 1) * 1024);
        a0 = __builtin_amdgcn_mfma_f32_32x32x16_bf16(wf[kt], b0, a0, 0, 0, 0);
        a1 = __builtin_amdgcn_mfma_f32_32x32x16_bf16(wf[kt + 1], b1, a1,
                                                     0, 0, 0);
      }
      asum = a0 + a1;
    }
    // ---- gates: asum[r]: gate g=r>>2, q=r&3 (cols hcol0+q), batch b ----
    float hout[4];
#pragma unroll
    for (int q = 0; q < 4; ++q) {
      float pa = asum[0 * 4 + q] + bf2f((unsigned short)((q < 2 ? xgn[0].x : xgn[0].y) >> ((q & 1) * 16)));
      float pi = asum[1 * 4 + q] + bf2f((unsigned short)((q < 2 ? xgn[1].x : xgn[1].y) >> ((q & 1) * 16)));
      float pf = asum[2 * 4 + q] + bf2f((unsigned short)((q < 2 ? xgn[2].x : xgn[2].y) >> ((q & 1) * 16)));
      float po = asum[3 * 4 + q] + bf2f((unsigned short)((q < 2 ? xgn[3].x : xgn[3].y) >> ((q & 1) * 16)));
      float a  = tanh_fast(pa);
      float ig = sigmoid_fast(pi);
      float fg = sigmoid_fast(pf);
      float og = sigmoid_fast(po);
      s4[q] = a * ig + s4[q] * fg;
      hout[q] = tanh_fast(s4[q]) * og;
    }
    // ---- publish h(t): coalesced 8B sc0sc1 store; block-aggregate flag ----
    {
      unsigned lo = (unsigned)f2bf(hout[0]) | ((unsigned)f2bf(hout[1]) << 16);
      unsigned hi = (unsigned)f2bf(hout[2]) | ((unsigned)f2bf(hout[3]) << 16);
      uint2 hd; hd.x = lo; hd.y = hi;
      const unsigned short* sbase = hbuf + (size_t)(t & 1) * 32768;
      asm volatile("global_store_dwordx2 %0, %1, %2 sc0 sc1"
                   :: "v"(st_voff), "v"(hd), "s"(sbase) : "memory");
      asm volatile("s_waitcnt vmcnt(0)" ::: "memory");
      __syncthreads();  // all 4 waves' h-stores at the coherence point;
                        // also bounds wave skew < 1 step (LDS parity safety)
      if (tid == 0)
        __hip_atomic_store(myflag, t + 1, __ATOMIC_RELAXED,
                           __HIP_MEMORY_SCOPE_AGENT);
    }
    // ---- off critical path: out store + next Xg prefetch ----
    f32x4 ov;
    ov[0] = hout[0]; ov[1] = hout[1]; ov[2] = hout[2]; ov[3] = hout[3];
    *(f32x4*)(out + ((size_t)t * 64 + b) * 512 + hcol0) = ov;
    const int tn = (t + 1 < TSTEPS) ? t + 1 : t;
#pragma unroll
    for (int g = 0; g < 4; ++g)
      xgn[g] = *(const uint2*)(Xg +
          ((((size_t)(tn * 4 + g) * 64 + mychunk) * 64 + b) * 8 + (l >> 5) * 4));
  }
}

// ---------------------------------------------------------------------------
// Workspace layout (bytes):
//   0          Xg bf16     134217728
//   134217728  Xbf bf16     33554432  (dead after gemm_xproj)
//   134217728  hbuf bf16      262144  (overlaps Xbf; no init needed)
//   167772160  WxT bf16      2097152
//   169869312  WhT bf16      2097152
//   171966464  biascat f32      8192
//   171974656  flags            4096  (zeroed)
// ---------------------------------------------------------------------------
extern "C" void kernel_launch(void* const* d_in, const int* in_sizes, int n_in,
                              void* d_out, int out_size, void* d_ws,
                              size_t ws_size, hipStream_t stream) {
  const float* X   = (const float*)d_in[0];
  const float* Wax = (const float*)d_in[1];
  const float* Wix = (const float*)d_in[2];
  const float* Wfx = (const float*)d_in[3];
  const float* Wox = (const float*)d_in[4];
  const float* Wah = (const float*)d_in[5];
  const float* Wih = (const float*)d_in[6];
  const float* Wfh = (const float*)d_in[7];
  const float* Woh = (const float*)d_in[8];
  const float* ba  = (const float*)d_in[9];
  const float* bi  = (const float*)d_in[10];
  const float* bf  = (const float*)d_in[11];
  const float* bo  = (const float*)d_in[12];

  char* ws = (char*)d_ws;
  unsigned short* Xg   = (unsigned short*)(ws);
  unsigned short* Xbf  = (unsigned short*)(ws + 134217728);
  unsigned short* hbuf = (unsigned short*)(ws + 134217728);  // reuses Xbf
  unsigned short* WxT  = (unsigned short*)(ws + 167772160);
  unsigned short* WhT  = (unsigned short*)(ws + 169869312);
  float*          bcat = (float*)(ws + 171966464);
  int*            flags= (int*)(ws + 171974656);

  hipMemsetAsync(ws + 171974656, 0, 4096, stream);  // flags = 0

  prep_wT<<<2048, 256, 0, stream>>>(Wax, Wix, Wfx, Wox, Wah, Wih, Wfh, Woh,
                                    WxT, WhT);
  prep_xbf<<<16384, 256, 0, stream>>>(X, Xbf);
  prep_bias<<<8, 256, 0, stream>>>(ba, bi, bf, bo, bcat);
  gemm_xproj<<<4096, 256, 0, stream>>>(Xbf, WxT, bcat, Xg);
  lstm_scan<<<32, 256, 0, stream>>>(Xg, WhT, hbuf, flags, (float*)d_out);
}